// Round 8
// baseline (422.571 us; speedup 1.0000x reference)
//
#include <hip/hip_runtime.h>
#include <hip/hip_cooperative_groups.h>
#include <cmath>

namespace cg = cooperative_groups;

// Shapes (fixed for this problem)
#define B_    2
#define N_    6
#define D_    128
#define Q_    2304      // 48*48
#define K_    576       // 24*24
#define NK_   3456      // N_*K_
#define HEADS_ 4
#define DH_   32
#define SCALE_ 0.17677669529663687f        // 1/sqrt(32)
#define SCLOG2E_ 0.25504672615621814f      // SCALE * log2(e)

typedef __attribute__((ext_vector_type(8))) short bf16x8;
typedef __attribute__((ext_vector_type(4))) float f32x4;

#if defined(__has_builtin)
#if __has_builtin(__builtin_amdgcn_cvt_pk_bf16_f32)
#define HAS_PK_BF16 1
#endif
#endif

static __device__ __forceinline__ unsigned short f2bf(float f) {
  union { float f; unsigned u; } x; x.f = f;
  unsigned u = x.u + 0x7fffu + ((x.u >> 16) & 1u);   // RNE
  return (unsigned short)(u >> 16);
}
static __device__ __forceinline__ unsigned pkbf(float a, float b) {
#ifdef HAS_PK_BF16
  typedef __attribute__((ext_vector_type(2))) __bf16 vbf2;
  union { vbf2 v; unsigned u; } cv;
  cv.v = __builtin_amdgcn_cvt_pk_bf16_f32(a, b);   // RNE pack, 1 inst
  return cv.u;
#else
  return (unsigned)f2bf(a) | ((unsigned)f2bf(b) << 16);
#endif
}

struct KArgs {
  const float *q, *k, *v, *skip;
  const float *lnq_g, *lnq_b, *lnk_g, *lnk_b, *lnv_g, *lnv_b;
  const float *Wq, *bq, *Wk, *bk, *Wv, *bv;
  const float *Wp, *bp, *pre_g, *pre_b, *W1, *b1, *W2, *b2, *post_g, *post_b;
  unsigned short *QPh, *KPh, *VPTh;
  unsigned short *WTq, *WTk, *WTv, *WTp, *WT1, *WT2;
  float *PO, *Pl, *out;
};

// ---------------------------------------------------------------------------
// Single cooperative mega-kernel: weight-prep -> qkv LN+proj -> attention ->
// fused tail, separated by grid.sync(). 26.9 KB LDS arena shared by phases;
// __launch_bounds__(256,5) guarantees 5 blocks/CU co-residency (1280 slots).
// ---------------------------------------------------------------------------
__global__ __launch_bounds__(256, 5) void k_mega(KArgs a)
{
  __shared__ __align__(16) char smem[26880];
  const int t = threadIdx.x;
  const int bid = blockIdx.x;
  const int gsz = gridDim.x;
  const int w = t >> 6, lane = t & 63, quad = lane >> 4, l16 = lane & 15;
  const f32x4 zf = {0.f, 0.f, 0.f, 0.f};

  // ========== phase P: transpose+convert weights to bf16 WT[n][k] ==========
  {
    float (*tile)[33] = (float (*)[33])smem;
    for (int wb = bid; wb < 128; wb += gsz) {
      const float* src; unsigned short* dst; int Kd, J, tl;
      if      (wb < 16) { src = a.Wq; dst = a.WTq; Kd = 128; J = 128; tl = wb; }
      else if (wb < 32) { src = a.Wk; dst = a.WTk; Kd = 128; J = 128; tl = wb - 16; }
      else if (wb < 48) { src = a.Wv; dst = a.WTv; Kd = 128; J = 128; tl = wb - 32; }
      else if (wb < 64) { src = a.Wp; dst = a.WTp; Kd = 128; J = 128; tl = wb - 48; }
      else if (wb < 96) { src = a.W1; dst = a.WT1; Kd = 128; J = 256; tl = wb - 64; }
      else              { src = a.W2; dst = a.WT2; Kd = 256; J = 128; tl = wb - 96; }
      const int njt = J >> 5;
      const int tj = tl % njt, tk = tl / njt;
#pragma unroll
      for (int i = 0; i < 4; ++i) {
        int idx = t + 256 * i;
        int r = idx >> 5, c = idx & 31;
        tile[r][c] = src[(size_t)(tk * 32 + r) * J + tj * 32 + c];
      }
      __syncthreads();
#pragma unroll
      for (int i = 0; i < 2; ++i) {
        int idx = t + 256 * i;
        int rr = idx >> 4, c2 = (idx & 15) << 1;
        *(unsigned*)&dst[(size_t)(tj * 32 + rr) * Kd + tk * 32 + c2] =
            pkbf(tile[c2][rr], tile[c2 + 1][rr]);
      }
      __syncthreads();
    }
  }
  cg::this_grid().sync();

  // ========== phase A: fused q/k/v LN + MFMA projection (1296 tiles) =======
  {
    float (*xs)[132] = (float (*)[132])smem;                          // 16896
    unsigned short (*xh)[136] = (unsigned short (*)[136])(smem + 16896); // 8704
    float* gs  = (float*)(smem + 25600);
    float* bs  = (float*)(smem + 26112);
    float* mu  = (float*)(smem + 26624);
    float* rsd = (float*)(smem + 26752);
    for (int tl = bid; tl < 1296; tl += gsz) {
      const float* x; const unsigned short* WT; const float* g; const float* bl;
      const float* bias; int S, blk, mode; float osc;
      if (tl < 864)       { mode = 0; blk = tl;        x = a.q; WT = a.WTq; g = a.lnq_g; bl = a.lnq_b; bias = a.bq; S = Q_; osc = SCLOG2E_; }
      else if (tl < 1080) { mode = 0; blk = tl - 864;  x = a.k; WT = a.WTk; g = a.lnk_g; bl = a.lnk_b; bias = a.bk; S = K_; osc = 1.0f; }
      else                { mode = 1; blk = tl - 1080; x = a.v; WT = a.WTv; g = a.lnv_g; bl = a.lnv_b; bias = a.bv; S = K_; osc = 1.0f; }
      const int ntile = S >> 5;
      const int o  = blk / ntile;
      const int s0 = (blk % ntile) << 5;

      if (t < 128) { gs[t] = g[t]; bs[t] = bl[t]; }
      const float* xb = x + (size_t)o * 128 * (size_t)S + s0;
#pragma unroll
      for (int i = 0; i < 4; ++i) {
        int idx = t + 256 * i;
        int c = idx >> 3, s4 = (idx & 7) << 2;
        float4 xv = *(const float4*)&xb[(size_t)c * S + s4];
        xs[s4 + 0][c] = xv.x; xs[s4 + 1][c] = xv.y;
        xs[s4 + 2][c] = xv.z; xs[s4 + 3][c] = xv.w;
      }
      __syncthreads();
      {
        int s = t >> 3, l8 = t & 7;
        float sum = 0.f, sq = 0.f;
        for (int c = l8; c < 128; c += 8) { float v = xs[s][c]; sum += v; sq += v * v; }
#pragma unroll
        for (int off = 4; off > 0; off >>= 1) {
          sum += __shfl_down(sum, off, 8);
          sq  += __shfl_down(sq,  off, 8);
        }
        if (l8 == 0) {
          float mth = sum * 0.0078125f;
          float var = sq * 0.0078125f - mth * mth;
          mu[s] = mth; rsd[s] = rsqrtf(var + 1e-5f);
        }
      }
      __syncthreads();
#pragma unroll
      for (int i = 0; i < 8; ++i) {
        int idx = t + 256 * i;
        int s = idx >> 6, c2 = (idx & 63) << 1;
        float y0 = (xs[s][c2]     - mu[s]) * rsd[s] * gs[c2]     + bs[c2];
        float y1 = (xs[s][c2 + 1] - mu[s]) * rsd[s] * gs[c2 + 1] + bs[c2 + 1];
        *(unsigned*)&xh[s][c2] = pkbf(y0, y1);
      }
      __syncthreads();
      f32x4 acc[2][2] = {{zf, zf}, {zf, zf}};
#pragma unroll
      for (int kc = 0; kc < 4; ++kc) {
        bf16x8 a0 = *(const bf16x8*)&xh[l16][kc * 32 + quad * 8];
        bf16x8 a1 = *(const bf16x8*)&xh[16 + l16][kc * 32 + quad * 8];
        bf16x8 b0 = *(const bf16x8*)&WT[(size_t)(w * 32 + l16) * 128 + kc * 32 + quad * 8];
        bf16x8 b1 = *(const bf16x8*)&WT[(size_t)(w * 32 + 16 + l16) * 128 + kc * 32 + quad * 8];
        acc[0][0] = __builtin_amdgcn_mfma_f32_16x16x32_bf16(a0, b0, acc[0][0], 0, 0, 0);
        acc[0][1] = __builtin_amdgcn_mfma_f32_16x16x32_bf16(a0, b1, acc[0][1], 0, 0, 0);
        acc[1][0] = __builtin_amdgcn_mfma_f32_16x16x32_bf16(a1, b0, acc[1][0], 0, 0, 0);
        acc[1][1] = __builtin_amdgcn_mfma_f32_16x16x32_bf16(a1, b1, acc[1][1], 0, 0, 0);
      }
      if (mode == 0) {
        unsigned short* outh = (tl < 864) ? a.QPh : a.KPh;
        __syncthreads();                      // xh reused as output staging
#pragma unroll
        for (int mt = 0; mt < 2; ++mt)
#pragma unroll
          for (int nt = 0; nt < 2; ++nt) {
            int col = w * 32 + nt * 16 + l16;
            float bc = bias[col];
#pragma unroll
            for (int r = 0; r < 4; ++r)
              xh[mt * 16 + quad * 4 + r][col] = f2bf((acc[mt][nt][r] + bc) * osc);
          }
        __syncthreads();
#pragma unroll
        for (int i = 0; i < 2; ++i) {
          int s = i * 16 + (t >> 4), c8 = (t & 15) << 3;
          *(uint4*)&outh[((size_t)o * S + s0 + s) * 128 + c8] = *(uint4*)&xh[s][c8];
        }
      } else {
        const int b = o / 6, n = o % 6;
#pragma unroll
        for (int mt = 0; mt < 2; ++mt)
#pragma unroll
          for (int nt = 0; nt < 2; ++nt) {
            int col = w * 32 + nt * 16 + l16;
            int hh = col >> 5, dh = col & 31;
            float bc = bias[col];
            ushort4 pk;
            *(unsigned*)&pk.x = pkbf(acc[mt][nt][0] + bc, acc[mt][nt][1] + bc);
            *(unsigned*)&pk.z = pkbf(acc[mt][nt][2] + bc, acc[mt][nt][3] + bc);
            int s = n * 576 + s0 + mt * 16 + quad * 4;
            *(ushort4*)&a.VPTh[((size_t)(b * 4 + hh) * 32 + dh) * (size_t)NK_ + s] = pk;
          }
      }
      __syncthreads();
    }
  }
  cg::this_grid().sync();

  // ========== phase B: MFMA flash attention (1152 tiles) ====================
  {
    unsigned short (*plds)[2][16][40] = (unsigned short (*)[2][16][40])smem; // 10240
    float (*ol)[16][32] = (float (*)[16][32])smem;                            // alias
    float (*ll)[2][4][16] = (float (*)[2][4][16])(smem + 10240);              // 2048
    for (int ab = bid; ab < 1152; ab += gsz) {
      const int qt = ab % 72;
      const int rest = ab / 72;            // 0..15
      const int bhx = rest >> 1, ks = rest & 1;
      const int bb = bhx >> 2, h = bhx & 3;
      const int q0 = qt << 5;

      const unsigned short* vbase = a.VPTh + (size_t)bhx * 32 * (size_t)NK_;
      f32x4 o00 = zf, o01 = zf, o10 = zf, o11 = zf;
      float lsum0 = 0.f, lsum1 = 0.f;

      const int m8 = ks * 4 + w;
      int c0 = (108 * m8) >> 3, c1 = (108 * (m8 + 1)) >> 3;   // 13-14 chunks

      while (c0 < c1) {
        const int nn = c0 / 18;
        const int cend = min(c1, (nn + 1) * 18);
        const unsigned short* kb = &a.KPh[((size_t)(bb * 6 + nn) * K_) * 128 + h * 32];
        const unsigned short* qb = &a.QPh[((size_t)(bb * 6 + nn) * Q_ + q0) * 128 + h * 32];
        bf16x8 qc0 = *(const bf16x8*)&qb[(size_t)l16 * 128 + quad * 8];
        bf16x8 qc1 = *(const bf16x8*)&qb[(size_t)(16 + l16) * 128 + quad * 8];

        int kl = (c0 - nn * 18) << 5;
        bf16x8 kf0 = *(const bf16x8*)&kb[(size_t)(kl + l16) * 128 + quad * 8];
        bf16x8 kf1 = *(const bf16x8*)&kb[(size_t)(kl + 16 + l16) * 128 + quad * 8];
        const unsigned short* vb = vbase + ((size_t)c0 << 5);
        bf16x8 vf0 = *(const bf16x8*)&vb[(size_t)l16 * NK_ + quad * 8];
        bf16x8 vf1 = *(const bf16x8*)&vb[(size_t)(16 + l16) * NK_ + quad * 8];

        for (int kc = c0; kc < cend; ++kc) {
          const int kln = (kc + 1 - nn * 18) << 5;   // unclamped prefetch
          bf16x8 nk0 = *(const bf16x8*)&kb[(size_t)(kln + l16) * 128 + quad * 8];
          bf16x8 nk1 = *(const bf16x8*)&kb[(size_t)(kln + 16 + l16) * 128 + quad * 8];
          const unsigned short* vbn = vbase + ((size_t)(kc + 1) << 5);
          bf16x8 nv0 = *(const bf16x8*)&vbn[(size_t)l16 * NK_ + quad * 8];
          bf16x8 nv1 = *(const bf16x8*)&vbn[(size_t)(16 + l16) * NK_ + quad * 8];

          f32x4 s00 = __builtin_amdgcn_mfma_f32_16x16x32_bf16(kf0, qc0, zf, 0, 0, 0);
          f32x4 s01 = __builtin_amdgcn_mfma_f32_16x16x32_bf16(kf1, qc0, zf, 0, 0, 0);
          f32x4 s10 = __builtin_amdgcn_mfma_f32_16x16x32_bf16(kf0, qc1, zf, 0, 0, 0);
          f32x4 s11 = __builtin_amdgcn_mfma_f32_16x16x32_bf16(kf1, qc1, zf, 0, 0, 0);

          // scores are in log2 domain (Q pre-scaled by SCALE*log2e): native exp2
          float a00 = exp2f(fminf(s00.x, 100.f)), a01 = exp2f(fminf(s00.y, 100.f));
          float a02 = exp2f(fminf(s00.z, 100.f)), a03 = exp2f(fminf(s00.w, 100.f));
          float a10 = exp2f(fminf(s01.x, 100.f)), a11 = exp2f(fminf(s01.y, 100.f));
          float a12 = exp2f(fminf(s01.z, 100.f)), a13 = exp2f(fminf(s01.w, 100.f));
          lsum0 += (a00 + a01 + a02 + a03) + (a10 + a11 + a12 + a13);
          float b00 = exp2f(fminf(s10.x, 100.f)), b01 = exp2f(fminf(s10.y, 100.f));
          float b02 = exp2f(fminf(s10.z, 100.f)), b03 = exp2f(fminf(s10.w, 100.f));
          float b10 = exp2f(fminf(s11.x, 100.f)), b11 = exp2f(fminf(s11.y, 100.f));
          float b12 = exp2f(fminf(s11.z, 100.f)), b13 = exp2f(fminf(s11.w, 100.f));
          lsum1 += (b00 + b01 + b02 + b03) + (b10 + b11 + b12 + b13);

          uint2 w0a; w0a.x = pkbf(a00, a01); w0a.y = pkbf(a02, a03);
          uint2 w0b; w0b.x = pkbf(a10, a11); w0b.y = pkbf(a12, a13);
          uint2 w1a; w1a.x = pkbf(b00, b01); w1a.y = pkbf(b02, b03);
          uint2 w1b; w1b.x = pkbf(b10, b11); w1b.y = pkbf(b12, b13);
          *(uint2*)&plds[w][0][l16][quad * 4]      = w0a;
          *(uint2*)&plds[w][0][l16][16 + quad * 4] = w0b;
          *(uint2*)&plds[w][1][l16][quad * 4]      = w1a;
          *(uint2*)&plds[w][1][l16][16 + quad * 4] = w1b;
          bf16x8 pf0 = *(const bf16x8*)&plds[w][0][l16][quad * 8];
          bf16x8 pf1 = *(const bf16x8*)&plds[w][1][l16][quad * 8];

          o00 = __builtin_amdgcn_mfma_f32_16x16x32_bf16(pf0, vf0, o00, 0, 0, 0);
          o01 = __builtin_amdgcn_mfma_f32_16x16x32_bf16(pf0, vf1, o01, 0, 0, 0);
          o10 = __builtin_amdgcn_mfma_f32_16x16x32_bf16(pf1, vf0, o10, 0, 0, 0);
          o11 = __builtin_amdgcn_mfma_f32_16x16x32_bf16(pf1, vf1, o11, 0, 0, 0);

          kf0 = nk0; kf1 = nk1; vf0 = nv0; vf1 = nv1;
        }
        c0 = cend;
      }

      ll[w][0][quad][l16] = lsum0;
      ll[w][1][quad][l16] = lsum1;
#pragma unroll
      for (int tt = 0; tt < 2; ++tt) {
        __syncthreads();
        f32x4 t0 = tt ? o10 : o00;
        f32x4 t1 = tt ? o11 : o01;
#pragma unroll
        for (int r = 0; r < 4; ++r) {
          ol[w][quad * 4 + r][l16]      = t0[r];
          ol[w][quad * 4 + r][16 + l16] = t1[r];
        }
        __syncthreads();
        const int q = t >> 4, i16 = t & 15, dd = i16 << 1;
        float a0 = 0.f, a1 = 0.f;
#pragma unroll
        for (int ww = 0; ww < 4; ++ww) { a0 += ol[ww][q][dd]; a1 += ol[ww][q][dd + 1]; }
        float2 r2; r2.x = a0; r2.y = a1;
        *(float2*)&a.PO[(((size_t)ks * 8 + bhx) * Q_ + q0 + tt * 16 + q) * 32 + dd] = r2;
        if (i16 == 0) {
          float l = 0.f;
#pragma unroll
          for (int ww = 0; ww < 4; ++ww)
#pragma unroll
            for (int qq = 0; qq < 4; ++qq) l += ll[ww][tt][qq][q];
          a.Pl[((size_t)ks * 8 + bhx) * Q_ + q0 + tt * 16 + q] = l;
        }
      }
      __syncthreads();
    }
  }
  cg::this_grid().sync();

  // ========== phase C: fused tail (288 tiles x 16 rows, 4 waves) ===========
  {
    float (*xs)[132] = (float (*)[132])smem;                            // 8448
    unsigned short (*xh)[136] = (unsigned short (*)[136])(smem + 8448); // 4352
    unsigned short (*hb)[264] = (unsigned short (*)[264])(smem + 12800);// 8448
    float* g1s = (float*)(smem + 21248);
    float* b1s = (float*)(smem + 21760);
    float* g2s = (float*)(smem + 22272);
    float* b2s = (float*)(smem + 22784);
    float* mu  = (float*)(smem + 23296);
    float* rsd = (float*)(smem + 23360);
    for (int tl = bid; tl < 288; tl += gsz) {
      const int row0 = tl << 4;
      const int bb = row0 / Q_, hw0 = row0 % Q_;

      if (t < 128) { g1s[t] = a.pre_g[t]; b1s[t] = a.pre_b[t]; g2s[t] = a.post_g[t]; b2s[t] = a.post_b[t]; }
      // stage 1: merge 2-way ksplit partials -> bf16 A-frags in xh
#pragma unroll
      for (int i = 0; i < 4; ++i) {
        int idx = t + 256 * i;               // 1024 pairs
        int s = idx >> 6, c2 = (idx & 63) << 1;
        int q = hw0 + s;
        int h = c2 >> 5, dh = c2 & 31;
        size_t bq = (size_t)(bb * 4 + h) * Q_ + q;
        size_t i0 = bq * 32 + dh;
        float2 p0 = *(const float2*)&a.PO[i0];
        float2 p1 = *(const float2*)&a.PO[589824 + i0];
        float inv = 1.f / (a.Pl[bq] + a.Pl[18432 + bq]);
        *(unsigned*)&xh[s][c2] = pkbf((p0.x + p1.x) * inv, (p0.y + p1.y) * inv);
      }
      __syncthreads();
      // stage 2: out-proj MFMA (wave w: cols w*32..w*32+31, two nt halves)
#pragma unroll
      for (int nt = 0; nt < 2; ++nt) {
        const int col = w * 32 + nt * 16 + l16;
        f32x4 acc = zf;
#pragma unroll
        for (int kc = 0; kc < 4; ++kc) {
          bf16x8 a0 = *(const bf16x8*)&xh[l16][kc * 32 + quad * 8];
          bf16x8 b0 = *(const bf16x8*)&a.WTp[(size_t)col * 128 + kc * 32 + quad * 8];
          acc = __builtin_amdgcn_mfma_f32_16x16x32_bf16(a0, b0, acc, 0, 0, 0);
        }
        float bc = a.bp[col];
        float4 sk = *(const float4*)&a.skip[((size_t)bb * 128 + col) * Q_ + hw0 + quad * 4];
        xs[quad * 4 + 0][col] = acc[0] + bc + sk.x;
        xs[quad * 4 + 1][col] = acc[1] + bc + sk.y;
        xs[quad * 4 + 2][col] = acc[2] + bc + sk.z;
        xs[quad * 4 + 3][col] = acc[3] + bc + sk.w;
      }
      __syncthreads();
      // stage 3: preLN (16 lanes per row)
      {
        int s = t >> 4, lg = t & 15;
        float sum = 0.f, sq = 0.f;
        for (int c = lg; c < 128; c += 16) { float v = xs[s][c]; sum += v; sq += v * v; }
#pragma unroll
        for (int off = 8; off > 0; off >>= 1) {
          sum += __shfl_down(sum, off, 16);
          sq  += __shfl_down(sq,  off, 16);
        }
        if (lg == 0) {
          float mth = sum * 0.0078125f;
          float var = sq * 0.0078125f - mth * mth;
          mu[s] = mth; rsd[s] = rsqrtf(var + 1e-5f);
        }
      }
      __syncthreads();
#pragma unroll
      for (int i = 0; i < 4; ++i) {
        int idx = t + 256 * i;
        int s = idx >> 6, c2 = (idx & 63) << 1;
        float y0 = (xs[s][c2]     - mu[s]) * rsd[s] * g1s[c2]     + b1s[c2];
        float y1 = (xs[s][c2 + 1] - mu[s]) * rsd[s] * g1s[c2 + 1] + b1s[c2 + 1];
        xs[s][c2] = y0; xs[s][c2 + 1] = y1;
        *(unsigned*)&xh[s][c2] = pkbf(y0, y1);
      }
      __syncthreads();
      // stage 4: fc1 + GELU (wave w: cols w*64 + nt*16, nt=0..3)
#pragma unroll
      for (int nt = 0; nt < 4; ++nt) {
        const int col = w * 64 + nt * 16 + l16;
        f32x4 acc = zf;
#pragma unroll
        for (int kc = 0; kc < 4; ++kc) {
          bf16x8 a0 = *(const bf16x8*)&xh[l16][kc * 32 + quad * 8];
          bf16x8 b0 = *(const bf16x8*)&a.WT1[(size_t)col * 128 + kc * 32 + quad * 8];
          acc = __builtin_amdgcn_mfma_f32_16x16x32_bf16(a0, b0, acc, 0, 0, 0);
        }
        float bc = a.b1[col];
#pragma unroll
        for (int r = 0; r < 4; ++r) {
          float hx = acc[r] + bc;
          hb[quad * 4 + r][col] =
              f2bf(0.5f * hx * (1.f + erff(hx * 0.7071067811865476f)));
        }
      }
      __syncthreads();
      // stage 5: fc2 (K=256) + residual (wave w: cols w*32 + nt*16, nt=0,1)
#pragma unroll
      for (int nt = 0; nt < 2; ++nt) {
        const int col = w * 32 + nt * 16 + l16;
        f32x4 acc = zf;
#pragma unroll
        for (int kc = 0; kc < 8; ++kc) {
          bf16x8 a0 = *(const bf16x8*)&hb[l16][kc * 32 + quad * 8];
          bf16x8 b0 = *(const bf16x8*)&a.WT2[(size_t)col * 256 + kc * 32 + quad * 8];
          acc = __builtin_amdgcn_mfma_f32_16x16x32_bf16(a0, b0, acc, 0, 0, 0);
        }
        float bc = a.b2[col];
#pragma unroll
        for (int r = 0; r < 4; ++r) {
          int row = quad * 4 + r;
          xs[row][col] = acc[r] + bc + xs[row][col];
        }
      }
      __syncthreads();
      // stage 6: postLN + transposed store
      {
        int s = t >> 4, lg = t & 15;
        float sum = 0.f, sq = 0.f;
        for (int c = lg; c < 128; c += 16) { float v = xs[s][c]; sum += v; sq += v * v; }
#pragma unroll
        for (int off = 8; off > 0; off >>= 1) {
          sum += __shfl_down(sum, off, 16);
          sq  += __shfl_down(sq,  off, 16);
        }
        if (lg == 0) {
          float mth = sum * 0.0078125f;
          float var = sq * 0.0078125f - mth * mth;
          mu[s] = mth; rsd[s] = rsqrtf(var + 1e-5f);
        }
      }
      __syncthreads();
#pragma unroll
      for (int i = 0; i < 8; ++i) {
        int idx = t + 256 * i;
        int s = idx & 15, c = idx >> 4;
        a.out[(size_t)bb * (128 * (size_t)Q_) + (size_t)c * Q_ + hw0 + s] =
            (xs[s][c] - mu[s]) * rsd[s] * g2s[c] + b2s[c];
      }
      __syncthreads();
    }
  }
}

// ---------------------------------------------------------------------------
extern "C" void kernel_launch(void* const* d_in, const int* in_sizes, int n_in,
                              void* d_out, int out_size, void* d_ws, size_t ws_size,
                              hipStream_t stream) {
  KArgs ka;
  ka.q     = (const float*)d_in[0];
  ka.k     = (const float*)d_in[1];
  ka.v     = (const float*)d_in[2];
  ka.skip  = (const float*)d_in[3];
  ka.lnq_g = (const float*)d_in[4];
  ka.lnq_b = (const float*)d_in[5];
  ka.Wq    = (const float*)d_in[6];
  ka.bq    = (const float*)d_in[7];
  ka.lnk_g = (const float*)d_in[8];
  ka.lnk_b = (const float*)d_in[9];
  ka.Wk    = (const float*)d_in[10];
  ka.bk    = (const float*)d_in[11];
  ka.lnv_g = (const float*)d_in[12];
  ka.lnv_b = (const float*)d_in[13];
  ka.Wv    = (const float*)d_in[14];
  ka.bv    = (const float*)d_in[15];
  ka.Wp    = (const float*)d_in[16];
  ka.bp    = (const float*)d_in[17];
  ka.pre_g = (const float*)d_in[18];
  ka.pre_b = (const float*)d_in[19];
  ka.W1    = (const float*)d_in[20];
  ka.b1    = (const float*)d_in[21];
  ka.W2    = (const float*)d_in[22];
  ka.b2    = (const float*)d_in[23];
  ka.post_g= (const float*)d_in[24];
  ka.post_b= (const float*)d_in[25];
  ka.out   = (float*)d_out;

  // Workspace layout (~16 MB)
  unsigned short* QPh  = (unsigned short*)d_ws;        // 3,538,944 h
  unsigned short* KPh  = QPh + 3538944;                //   884,736 h
  unsigned short* VPTh = KPh + 884736;                 //   884,736 h
  float* PO  = (float*)(VPTh + 884736);                // 1,179,648 f
  float* Pl  = PO + 1179648;                           //    36,864 f
  unsigned short* WTq = (unsigned short*)(Pl + 36864); //    16,384 h
  unsigned short* WTk = WTq + 16384;
  unsigned short* WTv = WTk + 16384;
  unsigned short* WTp = WTv + 16384;
  unsigned short* WT1 = WTp + 16384;                   //    32,768 h
  unsigned short* WT2 = WT1 + 32768;                   //    32,768 h
  ka.QPh = QPh; ka.KPh = KPh; ka.VPTh = VPTh;
  ka.PO = PO; ka.Pl = Pl;
  ka.WTq = WTq; ka.WTk = WTk; ka.WTv = WTv;
  ka.WTp = WTp; ka.WT1 = WT1; ka.WT2 = WT2;

  // Cooperative capacity: query occupancy, clamp grid (phases are
  // grid-stride so any grid >= 1 is correct; >= 1152 keeps attention
  // single-pass).
  int occ = 0;
  hipOccupancyMaxActiveBlocksPerMultiprocessor(&occ, k_mega, 256, 0);
  if (occ < 1) occ = 1;
  long long cap = (long long)occ * 256;
  int grid = (int)(cap < 1296 ? cap : 1296);

  void* params[] = { (void*)&ka };
  hipLaunchCooperativeKernel((const void*)k_mega, dim3(grid), dim3(256),
                             params, 0, stream);
}

// Round 9
// 175.337 us; speedup vs baseline: 2.4101x; 2.4101x over previous
//
#include <hip/hip_runtime.h>
#include <cmath>

// Shapes (fixed for this problem)
#define B_    2
#define N_    6
#define D_    128
#define Q_    2304      // 48*48
#define K_    576       // 24*24
#define NK_   3456      // N_*K_
#define HEADS_ 4
#define DH_   32
#define SCALE_ 0.17677669529663687f        // 1/sqrt(32)
#define SCLOG2E_ 0.25504672615621814f      // SCALE * log2(e)

typedef __attribute__((ext_vector_type(8))) short bf16x8;
typedef __attribute__((ext_vector_type(4))) float f32x4;

#if defined(__has_builtin)
#if __has_builtin(__builtin_amdgcn_cvt_pk_bf16_f32)
#define HAS_PK_BF16 1
#endif
#endif

static __device__ __forceinline__ unsigned short f2bf(float f) {
  union { float f; unsigned u; } x; x.f = f;
  unsigned u = x.u + 0x7fffu + ((x.u >> 16) & 1u);   // RNE
  return (unsigned short)(u >> 16);
}
static __device__ __forceinline__ unsigned pkbf(float a, float b) {
#ifdef HAS_PK_BF16
  typedef __attribute__((ext_vector_type(2))) __bf16 vbf2;
  union { vbf2 v; unsigned u; } cv;
  cv.v = __builtin_amdgcn_cvt_pk_bf16_f32(a, b);   // RNE pack, 1 inst
  return cv.u;
#else
  return (unsigned)f2bf(a) | ((unsigned)f2bf(b) << 16);
#endif
}

// ---------------------------------------------------------------------------
// Kernel P: transpose+convert all weights to bf16 WT[n][k] (MFMA B-frag
// layout). 128 blocks, one 32x32 tile each.
// ---------------------------------------------------------------------------
__global__ __launch_bounds__(256) void k_prep_wt(
    const float* __restrict__ Wq, const float* __restrict__ Wk,
    const float* __restrict__ Wv, const float* __restrict__ Wp,
    const float* __restrict__ W1, const float* __restrict__ W2,
    unsigned short* __restrict__ WTq, unsigned short* __restrict__ WTk,
    unsigned short* __restrict__ WTv, unsigned short* __restrict__ WTp,
    unsigned short* __restrict__ WT1, unsigned short* __restrict__ WT2)
{
  __shared__ float tile[32][33];
  const int wb = blockIdx.x, t = threadIdx.x;
  const float* src; unsigned short* dst; int Kd, J, tl;
  if      (wb < 16) { src = Wq; dst = WTq; Kd = 128; J = 128; tl = wb; }
  else if (wb < 32) { src = Wk; dst = WTk; Kd = 128; J = 128; tl = wb - 16; }
  else if (wb < 48) { src = Wv; dst = WTv; Kd = 128; J = 128; tl = wb - 32; }
  else if (wb < 64) { src = Wp; dst = WTp; Kd = 128; J = 128; tl = wb - 48; }
  else if (wb < 96) { src = W1; dst = WT1; Kd = 128; J = 256; tl = wb - 64; }
  else              { src = W2; dst = WT2; Kd = 256; J = 128; tl = wb - 96; }
  const int njt = J >> 5;
  const int tj = tl % njt, tk = tl / njt;
#pragma unroll
  for (int i = 0; i < 4; ++i) {
    int idx = t + 256 * i;
    int r = idx >> 5, c = idx & 31;
    tile[r][c] = src[(size_t)(tk * 32 + r) * J + tj * 32 + c];
  }
  __syncthreads();
#pragma unroll
  for (int i = 0; i < 2; ++i) {
    int idx = t + 256 * i;               // 512 pairs
    int rr = idx >> 4, c2 = (idx & 15) << 1;
    *(unsigned*)&dst[(size_t)(tj * 32 + rr) * Kd + tk * 32 + c2] =
        pkbf(tile[c2][rr], tile[c2 + 1][rr]);
  }
}

// ---------------------------------------------------------------------------
// Kernel A: fused q/k/v LN + MFMA projection (single dispatch, 1296 blocks).
// Q output is pre-scaled by SCALE*log2(e) so attention uses native exp2.
// ---------------------------------------------------------------------------
__global__ __launch_bounds__(256) void k_ln_proj_all(
    const float* __restrict__ qin, const float* __restrict__ kin,
    const float* __restrict__ vin,
    const float* __restrict__ lnq_g, const float* __restrict__ lnq_b,
    const float* __restrict__ lnk_g, const float* __restrict__ lnk_b,
    const float* __restrict__ lnv_g, const float* __restrict__ lnv_b,
    const unsigned short* __restrict__ WTq, const unsigned short* __restrict__ WTk,
    const unsigned short* __restrict__ WTv,
    const float* __restrict__ bq, const float* __restrict__ bk,
    const float* __restrict__ bv,
    unsigned short* __restrict__ QPh, unsigned short* __restrict__ KPh,
    unsigned short* __restrict__ VPTh)
{
  __shared__ float xs[32][132];
  __shared__ unsigned short xh[32][136];
  __shared__ float gs[128], bs[128];
  __shared__ float mu[32], rsd[32];
  const int t = threadIdx.x;
  const int bid = blockIdx.x;

  const float* x; const unsigned short* WT; const float* g; const float* bl;
  const float* bias; int S, blk, mode; float osc;
  if (bid < 864)       { mode = 0; blk = bid;        x = qin; WT = WTq; g = lnq_g; bl = lnq_b; bias = bq; S = Q_; osc = SCLOG2E_; }
  else if (bid < 1080) { mode = 0; blk = bid - 864;  x = kin; WT = WTk; g = lnk_g; bl = lnk_b; bias = bk; S = K_; osc = 1.0f; }
  else                 { mode = 1; blk = bid - 1080; x = vin; WT = WTv; g = lnv_g; bl = lnv_b; bias = bv; S = K_; osc = 1.0f; }
  const int ntile = S >> 5;
  const int o  = blk / ntile;
  const int s0 = (blk % ntile) << 5;

  if (t < 128) { gs[t] = g[t]; bs[t] = bl[t]; }
  const float* xb = x + (size_t)o * 128 * (size_t)S + s0;
#pragma unroll
  for (int i = 0; i < 4; ++i) {
    int idx = t + 256 * i;
    int c = idx >> 3, s4 = (idx & 7) << 2;
    float4 xv = *(const float4*)&xb[(size_t)c * S + s4];
    xs[s4 + 0][c] = xv.x; xs[s4 + 1][c] = xv.y;
    xs[s4 + 2][c] = xv.z; xs[s4 + 3][c] = xv.w;
  }
  __syncthreads();
  {
    int s = t >> 3, l8 = t & 7;
    float sum = 0.f, sq = 0.f;
    for (int c = l8; c < 128; c += 8) { float v = xs[s][c]; sum += v; sq += v * v; }
#pragma unroll
    for (int off = 4; off > 0; off >>= 1) {
      sum += __shfl_down(sum, off, 8);
      sq  += __shfl_down(sq,  off, 8);
    }
    if (l8 == 0) {
      float mth = sum * 0.0078125f;
      float var = sq * 0.0078125f - mth * mth;
      mu[s] = mth; rsd[s] = rsqrtf(var + 1e-5f);
    }
  }
  __syncthreads();
#pragma unroll
  for (int i = 0; i < 8; ++i) {
    int idx = t + 256 * i;               // 2048 pairs
    int s = idx >> 6, c2 = (idx & 63) << 1;
    float y0 = (xs[s][c2]     - mu[s]) * rsd[s] * gs[c2]     + bs[c2];
    float y1 = (xs[s][c2 + 1] - mu[s]) * rsd[s] * gs[c2 + 1] + bs[c2 + 1];
    *(unsigned*)&xh[s][c2] = pkbf(y0, y1);
  }
  __syncthreads();
  const int w = t >> 6, lane = t & 63, quad = lane >> 4, l16 = lane & 15;
  const f32x4 zf = {0.f, 0.f, 0.f, 0.f};
  f32x4 acc[2][2] = {{zf, zf}, {zf, zf}};
#pragma unroll
  for (int kc = 0; kc < 4; ++kc) {
    bf16x8 a0 = *(const bf16x8*)&xh[l16][kc * 32 + quad * 8];
    bf16x8 a1 = *(const bf16x8*)&xh[16 + l16][kc * 32 + quad * 8];
    bf16x8 b0 = *(const bf16x8*)&WT[(size_t)(w * 32 + l16) * 128 + kc * 32 + quad * 8];
    bf16x8 b1 = *(const bf16x8*)&WT[(size_t)(w * 32 + 16 + l16) * 128 + kc * 32 + quad * 8];
    acc[0][0] = __builtin_amdgcn_mfma_f32_16x16x32_bf16(a0, b0, acc[0][0], 0, 0, 0);
    acc[0][1] = __builtin_amdgcn_mfma_f32_16x16x32_bf16(a0, b1, acc[0][1], 0, 0, 0);
    acc[1][0] = __builtin_amdgcn_mfma_f32_16x16x32_bf16(a1, b0, acc[1][0], 0, 0, 0);
    acc[1][1] = __builtin_amdgcn_mfma_f32_16x16x32_bf16(a1, b1, acc[1][1], 0, 0, 0);
  }
  if (mode == 0) {
    unsigned short* outh = (bid < 864) ? QPh : KPh;
    __syncthreads();                      // xh reused as output staging
#pragma unroll
    for (int mt = 0; mt < 2; ++mt)
#pragma unroll
      for (int nt = 0; nt < 2; ++nt) {
        int col = w * 32 + nt * 16 + l16;
        float bc = bias[col];
#pragma unroll
        for (int r = 0; r < 4; ++r)
          xh[mt * 16 + quad * 4 + r][col] = f2bf((acc[mt][nt][r] + bc) * osc);
      }
    __syncthreads();
#pragma unroll
    for (int i = 0; i < 2; ++i) {
      int s = i * 16 + (t >> 4), c8 = (t & 15) << 3;
      *(uint4*)&outh[((size_t)o * S + s0 + s) * 128 + c8] = *(uint4*)&xh[s][c8];
    }
  } else {
    const int b = o / 6, n = o % 6;
#pragma unroll
    for (int mt = 0; mt < 2; ++mt)
#pragma unroll
      for (int nt = 0; nt < 2; ++nt) {
        int col = w * 32 + nt * 16 + l16;
        int hh = col >> 5, dh = col & 31;
        float bc = bias[col];
        ushort4 pk;
        *(unsigned*)&pk.x = pkbf(acc[mt][nt][0] + bc, acc[mt][nt][1] + bc);
        *(unsigned*)&pk.z = pkbf(acc[mt][nt][2] + bc, acc[mt][nt][3] + bc);
        int s = n * 576 + s0 + mt * 16 + quad * 4;
        *(ushort4*)&VPTh[((size_t)(b * 4 + hh) * 32 + dh) * (size_t)NK_ + s] = pk;
      }
  }
}

// ---------------------------------------------------------------------------
// Kernel B: MFMA flash attention, software-pipelined: iteration kc processes
// the scores of chunk kc (exp2/pack/LDS/PV) while chunk kc+1's global loads
// are in flight, then issues QK MFMAs for kc+1. Double-buffered P-tile LDS
// removes the write-after-read dependency. No-max softmax in log2 domain
// (Q pre-scaled); no clamp (|scores| <= ~1). Split-K 2, two q-tiles/wave.
// Grid: 72 x 8 x 2 = 1152 blocks.
// ---------------------------------------------------------------------------
__global__ __launch_bounds__(256) void k_attn_mfma(
    const unsigned short* __restrict__ QPh, const unsigned short* __restrict__ KPh,
    const unsigned short* __restrict__ VPTh, float* __restrict__ PO,
    float* __restrict__ Pl)
{
  __shared__ __align__(16) char smem_u[20480];  // plds (20480 B) / ol (8192 B)
  typedef unsigned short plds_t[2][2][16][40];  // [buf][tile][row][40h]
  plds_t* plds = (plds_t*)smem_u;               // indexed [w]
  float (*ol)[16][32] = (float (*)[16][32])smem_u;
  __shared__ float ll[4][2][4][16];
  const int t = threadIdx.x;
  const int w = t >> 6, lane = t & 63;
  const int quad = lane >> 4, l16 = lane & 15;
  const int qt = blockIdx.x % 72;
  const int rest = blockIdx.x / 72;            // 0..15
  const int bhx = rest >> 1, ks = rest & 1;
  const int bb = bhx >> 2, h = bhx & 3;
  const int q0 = qt << 5;

  const unsigned short* vbase = VPTh + (size_t)bhx * 32 * (size_t)NK_;
  const f32x4 zf = {0.f, 0.f, 0.f, 0.f};
  f32x4 o00 = zf, o01 = zf, o10 = zf, o11 = zf;
  float lsum0 = 0.f, lsum1 = 0.f;
  int buf = 0;

  const int m8 = ks * 4 + w;
  int c0 = (108 * m8) >> 3, c1 = (108 * (m8 + 1)) >> 3;   // 13-14 chunks

  while (c0 < c1) {
    const int nn = c0 / 18;
    const int cend = min(c1, (nn + 1) * 18);
    const unsigned short* kb = &KPh[((size_t)(bb * 6 + nn) * K_) * 128 + h * 32];
    const unsigned short* qb = &QPh[((size_t)(bb * 6 + nn) * Q_ + q0) * 128 + h * 32];
    bf16x8 qc0 = *(const bf16x8*)&qb[(size_t)l16 * 128 + quad * 8];
    bf16x8 qc1 = *(const bf16x8*)&qb[(size_t)(16 + l16) * 128 + quad * 8];

    // prologue: load chunk c0, compute its scores
    int kl = (c0 - nn * 18) << 5;
    bf16x8 kf0 = *(const bf16x8*)&kb[(size_t)(kl + l16) * 128 + quad * 8];
    bf16x8 kf1 = *(const bf16x8*)&kb[(size_t)(kl + 16 + l16) * 128 + quad * 8];
    const unsigned short* vb = vbase + ((size_t)c0 << 5);
    bf16x8 pv0 = *(const bf16x8*)&vb[(size_t)l16 * NK_ + quad * 8];
    bf16x8 pv1 = *(const bf16x8*)&vb[(size_t)(16 + l16) * NK_ + quad * 8];
    f32x4 s00 = __builtin_amdgcn_mfma_f32_16x16x32_bf16(kf0, qc0, zf, 0, 0, 0);
    f32x4 s01 = __builtin_amdgcn_mfma_f32_16x16x32_bf16(kf1, qc0, zf, 0, 0, 0);
    f32x4 s10 = __builtin_amdgcn_mfma_f32_16x16x32_bf16(kf0, qc1, zf, 0, 0, 0);
    f32x4 s11 = __builtin_amdgcn_mfma_f32_16x16x32_bf16(kf1, qc1, zf, 0, 0, 0);

    for (int kc = c0; kc < cend; ++kc) {
      // issue loads for chunk kc+1 (unclamped prefetch; overrun reads stay
      // inside d_ws and are never consumed)
      const int kln = (kc + 1 - nn * 18) << 5;
      bf16x8 nk0 = *(const bf16x8*)&kb[(size_t)(kln + l16) * 128 + quad * 8];
      bf16x8 nk1 = *(const bf16x8*)&kb[(size_t)(kln + 16 + l16) * 128 + quad * 8];
      const unsigned short* vbn = vbase + ((size_t)(kc + 1) << 5);
      bf16x8 nv0 = *(const bf16x8*)&vbn[(size_t)l16 * NK_ + quad * 8];
      bf16x8 nv1 = *(const bf16x8*)&vbn[(size_t)(16 + l16) * NK_ + quad * 8];

      // process pending scores of chunk kc (log2 domain -> native exp2)
      float a00 = exp2f(s00.x), a01 = exp2f(s00.y);
      float a02 = exp2f(s00.z), a03 = exp2f(s00.w);
      float a10 = exp2f(s01.x), a11 = exp2f(s01.y);
      float a12 = exp2f(s01.z), a13 = exp2f(s01.w);
      lsum0 += (a00 + a01 + a02 + a03) + (a10 + a11 + a12 + a13);
      float b00 = exp2f(s10.x), b01 = exp2f(s10.y);
      float b02 = exp2f(s10.z), b03 = exp2f(s10.w);
      float b10 = exp2f(s11.x), b11 = exp2f(s11.y);
      float b12 = exp2f(s11.z), b13 = exp2f(s11.w);
      lsum1 += (b00 + b01 + b02 + b03) + (b10 + b11 + b12 + b13);

      uint2 w0a; w0a.x = pkbf(a00, a01); w0a.y = pkbf(a02, a03);
      uint2 w0b; w0b.x = pkbf(a10, a11); w0b.y = pkbf(a12, a13);
      uint2 w1a; w1a.x = pkbf(b00, b01); w1a.y = pkbf(b02, b03);
      uint2 w1b; w1b.x = pkbf(b10, b11); w1b.y = pkbf(b12, b13);
      *(uint2*)&plds[w][buf][0][l16][quad * 4]      = w0a;
      *(uint2*)&plds[w][buf][0][l16][16 + quad * 4] = w0b;
      *(uint2*)&plds[w][buf][1][l16][quad * 4]      = w1a;
      *(uint2*)&plds[w][buf][1][l16][16 + quad * 4] = w1b;
      bf16x8 pf0 = *(const bf16x8*)&plds[w][buf][0][l16][quad * 8];
      bf16x8 pf1 = *(const bf16x8*)&plds[w][buf][1][l16][quad * 8];

      o00 = __builtin_amdgcn_mfma_f32_16x16x32_bf16(pf0, pv0, o00, 0, 0, 0);
      o01 = __builtin_amdgcn_mfma_f32_16x16x32_bf16(pf0, pv1, o01, 0, 0, 0);
      o10 = __builtin_amdgcn_mfma_f32_16x16x32_bf16(pf1, pv0, o10, 0, 0, 0);
      o11 = __builtin_amdgcn_mfma_f32_16x16x32_bf16(pf1, pv1, o11, 0, 0, 0);

      // QK for chunk kc+1 (result consumed next iteration; discarded if
      // kc+1 == cend — the next segment prologue or epilogue ignores it)
      s00 = __builtin_amdgcn_mfma_f32_16x16x32_bf16(nk0, qc0, zf, 0, 0, 0);
      s01 = __builtin_amdgcn_mfma_f32_16x16x32_bf16(nk1, qc0, zf, 0, 0, 0);
      s10 = __builtin_amdgcn_mfma_f32_16x16x32_bf16(nk0, qc1, zf, 0, 0, 0);
      s11 = __builtin_amdgcn_mfma_f32_16x16x32_bf16(nk1, qc1, zf, 0, 0, 0);
      pv0 = nv0; pv1 = nv1;
      buf ^= 1;
    }
    c0 = cend;
  }

  ll[w][0][quad][l16] = lsum0;      // ll not aliased; safe pre-barrier
  ll[w][1][quad][l16] = lsum1;
#pragma unroll
  for (int tt = 0; tt < 2; ++tt) {
    __syncthreads();                 // first iter: all waves done with plds
    f32x4 t0 = tt ? o10 : o00;
    f32x4 t1 = tt ? o11 : o01;
#pragma unroll
    for (int r = 0; r < 4; ++r) {
      ol[w][quad * 4 + r][l16]      = t0[r];
      ol[w][quad * 4 + r][16 + l16] = t1[r];
    }
    __syncthreads();
    const int q = t >> 4, i16 = t & 15, dd = i16 << 1;
    float a0 = 0.f, a1 = 0.f;
#pragma unroll
    for (int ww = 0; ww < 4; ++ww) { a0 += ol[ww][q][dd]; a1 += ol[ww][q][dd + 1]; }
    float2 r2; r2.x = a0; r2.y = a1;
    *(float2*)&PO[(((size_t)ks * 8 + bhx) * Q_ + q0 + tt * 16 + q) * 32 + dd] = r2;
    if (i16 == 0) {
      float l = 0.f;
#pragma unroll
      for (int ww = 0; ww < 4; ++ww)
#pragma unroll
        for (int qq = 0; qq < 4; ++qq) l += ll[ww][tt][qq][q];
      Pl[((size_t)ks * 8 + bhx) * Q_ + q0 + tt * 16 + q] = l;
    }
  }
}

// ---------------------------------------------------------------------------
// Kernel C (fused tail, 512 threads, 16 rows/block, 288 blocks): 2-way
// ksplit-merge + out-proj + skip + preLN + fc1 + GELU + fc2 + residual
// + postLN + transposed store.
// ---------------------------------------------------------------------------
__global__ __launch_bounds__(512) void k_tail(
    const float* __restrict__ PO, const float* __restrict__ Pl,
    const unsigned short* __restrict__ WTp, const float* __restrict__ bp,
    const float* __restrict__ skip,
    const float* __restrict__ pre_g, const float* __restrict__ pre_b,
    const unsigned short* __restrict__ WT1, const float* __restrict__ b1,
    const unsigned short* __restrict__ WT2, const float* __restrict__ b2,
    const float* __restrict__ post_g, const float* __restrict__ post_b,
    float* __restrict__ out)
{
  __shared__ float xs[16][132];
  __shared__ unsigned short xh[16][136];
  __shared__ unsigned short hb[16][264];
  __shared__ float g1s[128], b1s[128], g2s[128], b2s[128];
  __shared__ float mu[16], rsd[16];
  const int t = threadIdx.x;
  const int row0 = blockIdx.x << 4;
  const int bb = row0 / Q_, hw0 = row0 % Q_;
  const int w = t >> 6, lane = t & 63, quad = lane >> 4, l16 = lane & 15;
  const f32x4 zf = {0.f, 0.f, 0.f, 0.f};

  if (t < 128) { g1s[t] = pre_g[t]; b1s[t] = pre_b[t]; g2s[t] = post_g[t]; b2s[t] = post_b[t]; }
  // --- stage 1: merge 2-way ksplit partials -> bf16 A-frags in xh
#pragma unroll
  for (int i = 0; i < 2; ++i) {
    int idx = t + 512 * i;               // 1024 pairs
    int s = idx >> 6, c2 = (idx & 63) << 1;
    int q = hw0 + s;
    int h = c2 >> 5, dh = c2 & 31;
    size_t bq = (size_t)(bb * 4 + h) * Q_ + q;
    size_t i0 = bq * 32 + dh;
    float2 p0 = *(const float2*)&PO[i0];
    float2 p1 = *(const float2*)&PO[589824 + i0];
    float inv = 1.f / (Pl[bq] + Pl[18432 + bq]);
    *(unsigned*)&xh[s][c2] = pkbf((p0.x + p1.x) * inv, (p0.y + p1.y) * inv);
  }
  __syncthreads();
  // --- stage 2: out-projection MFMA (wave w: cols w*16..w*16+15)
  {
    f32x4 acc = zf;
    const int col = w * 16 + l16;
#pragma unroll
    for (int kc = 0; kc < 4; ++kc) {
      bf16x8 a0 = *(const bf16x8*)&xh[l16][kc * 32 + quad * 8];
      bf16x8 b0 = *(const bf16x8*)&WTp[(size_t)col * 128 + kc * 32 + quad * 8];
      acc = __builtin_amdgcn_mfma_f32_16x16x32_bf16(a0, b0, acc, 0, 0, 0);
    }
    float bc = bp[col];
    float4 sk = *(const float4*)&skip[((size_t)bb * 128 + col) * Q_ + hw0 + quad * 4];
    xs[quad * 4 + 0][col] = acc[0] + bc + sk.x;
    xs[quad * 4 + 1][col] = acc[1] + bc + sk.y;
    xs[quad * 4 + 2][col] = acc[2] + bc + sk.z;
    xs[quad * 4 + 3][col] = acc[3] + bc + sk.w;
  }
  __syncthreads();
  // --- stage 3: preLN (32 lanes per row)
  {
    int s = t >> 5, lg = t & 31;
    float sum = 0.f, sq = 0.f;
    for (int c = lg; c < 128; c += 32) { float v = xs[s][c]; sum += v; sq += v * v; }
#pragma unroll
    for (int off = 16; off > 0; off >>= 1) {
      sum += __shfl_down(sum, off, 32);
      sq  += __shfl_down(sq,  off, 32);
    }
    if (lg == 0) {
      float mth = sum * 0.0078125f;
      float var = sq * 0.0078125f - mth * mth;
      mu[s] = mth; rsd[s] = rsqrtf(var + 1e-5f);
    }
  }
  __syncthreads();
#pragma unroll
  for (int i = 0; i < 2; ++i) {
    int idx = t + 512 * i;
    int s = idx >> 6, c2 = (idx & 63) << 1;
    float y0 = (xs[s][c2]     - mu[s]) * rsd[s] * g1s[c2]     + b1s[c2];
    float y1 = (xs[s][c2 + 1] - mu[s]) * rsd[s] * g1s[c2 + 1] + b1s[c2 + 1];
    xs[s][c2] = y0; xs[s][c2 + 1] = y1;
    *(unsigned*)&xh[s][c2] = pkbf(y0, y1);
  }
  __syncthreads();
  // --- stage 4: fc1 + GELU (wave w: cols w*32..w*32+31 of 256)
  {
#pragma unroll
    for (int nt = 0; nt < 2; ++nt) {
      const int col = w * 32 + nt * 16 + l16;
      f32x4 acc = zf;
#pragma unroll
      for (int kc = 0; kc < 4; ++kc) {
        bf16x8 a0 = *(const bf16x8*)&xh[l16][kc * 32 + quad * 8];
        bf16x8 b0 = *(const bf16x8*)&WT1[(size_t)col * 128 + kc * 32 + quad * 8];
        acc = __builtin_amdgcn_mfma_f32_16x16x32_bf16(a0, b0, acc, 0, 0, 0);
      }
      float bc = b1[col];
#pragma unroll
      for (int r = 0; r < 4; ++r) {
        float hx = acc[r] + bc;
        hb[quad * 4 + r][col] =
            f2bf(0.5f * hx * (1.f + erff(hx * 0.7071067811865476f)));
      }
    }
  }
  __syncthreads();
  // --- stage 5: fc2 (K=256) + residual z (wave w: cols w*16..w*16+15)
  {
    f32x4 acc = zf;
    const int col = w * 16 + l16;
#pragma unroll
    for (int kc = 0; kc < 8; ++kc) {
      bf16x8 a0 = *(const bf16x8*)&hb[l16][kc * 32 + quad * 8];
      bf16x8 b0 = *(const bf16x8*)&WT2[(size_t)col * 256 + kc * 32 + quad * 8];
      acc = __builtin_amdgcn_mfma_f32_16x16x32_bf16(a0, b0, acc, 0, 0, 0);
    }
    float bc = b2[col];
#pragma unroll
    for (int r = 0; r < 4; ++r) {
      int row = quad * 4 + r;
      xs[row][col] = acc[r] + bc + xs[row][col];
    }
  }
  __syncthreads();
  // --- stage 6: postLN + transposed store
  {
    int s = t >> 5, lg = t & 31;
    float sum = 0.f, sq = 0.f;
    for (int c = lg; c < 128; c += 32) { float v = xs[s][c]; sum += v; sq += v * v; }
#pragma unroll
    for (int off = 16; off > 0; off >>= 1) {
      sum += __shfl_down(sum, off, 32);
      sq  += __shfl_down(sq,  off, 32);
    }
    if (lg == 0) {
      float mth = sum * 0.0078125f;
      float var = sq * 0.0078125f - mth * mth;
      mu[s] = mth; rsd[s] = rsqrtf(var + 1e-5f);
    }
  }
  __syncthreads();
#pragma unroll
  for (int i = 0; i < 4; ++i) {
    int idx = t + 512 * i;
    int s = idx & 15, c = idx >> 4;
    out[(size_t)bb * (128 * (size_t)Q_) + (size_t)c * Q_ + hw0 + s] =
        (xs[s][c] - mu[s]) * rsd[s] * g2s[c] + b2s[c];
  }
}

// ---------------------------------------------------------------------------
extern "C" void kernel_launch(void* const* d_in, const int* in_sizes, int n_in,
                              void* d_out, int out_size, void* d_ws, size_t ws_size,
                              hipStream_t stream) {
  const float* q     = (const float*)d_in[0];
  const float* k     = (const float*)d_in[1];
  const float* v     = (const float*)d_in[2];
  const float* skip  = (const float*)d_in[3];
  const float* lnq_g = (const float*)d_in[4];
  const float* lnq_b = (const float*)d_in[5];
  const float* Wq    = (const float*)d_in[6];
  const float* bq    = (const float*)d_in[7];
  const float* lnk_g = (const float*)d_in[8];
  const float* lnk_b = (const float*)d_in[9];
  const float* Wk    = (const float*)d_in[10];
  const float* bk    = (const float*)d_in[11];
  const float* lnv_g = (const float*)d_in[12];
  const float* lnv_b = (const float*)d_in[13];
  const float* Wv    = (const float*)d_in[14];
  const float* bvv   = (const float*)d_in[15];
  const float* Wp    = (const float*)d_in[16];
  const float* bp    = (const float*)d_in[17];
  const float* pre_g = (const float*)d_in[18];
  const float* pre_b = (const float*)d_in[19];
  const float* W1    = (const float*)d_in[20];
  const float* b1    = (const float*)d_in[21];
  const float* W2    = (const float*)d_in[22];
  const float* b2    = (const float*)d_in[23];
  const float* post_g= (const float*)d_in[24];
  const float* post_b= (const float*)d_in[25];
  float* out = (float*)d_out;

  // Workspace layout (~16 MB)
  unsigned short* QPh  = (unsigned short*)d_ws;        // 3,538,944 h
  unsigned short* KPh  = QPh + 3538944;                //   884,736 h
  unsigned short* VPTh = KPh + 884736;                 //   884,736 h
  float* PO  = (float*)(VPTh + 884736);                // 1,179,648 f (2 partials)
  float* Pl  = PO + 1179648;                           //    36,864 f
  unsigned short* WTq = (unsigned short*)(Pl + 36864); //    16,384 h
  unsigned short* WTk = WTq + 16384;                   //    16,384 h
  unsigned short* WTv = WTk + 16384;                   //    16,384 h
  unsigned short* WTp = WTv + 16384;                   //    16,384 h
  unsigned short* WT1 = WTp + 16384;                   //    32,768 h
  unsigned short* WT2 = WT1 + 32768;                   //    32,768 h

  k_prep_wt<<<dim3(128), dim3(256), 0, stream>>>(Wq, Wk, Wv, Wp, W1, W2,
                                                 WTq, WTk, WTv, WTp, WT1, WT2);
  k_ln_proj_all<<<dim3(1296), dim3(256), 0, stream>>>(
      q, k, v, lnq_g, lnq_b, lnk_g, lnk_b, lnv_g, lnv_b,
      WTq, WTk, WTv, bq, bk, bvv, QPh, KPh, VPTh);
  k_attn_mfma<<<dim3(1152), dim3(256), 0, stream>>>(QPh, KPh, VPTh, PO, Pl);
  k_tail<<<dim3(288), dim3(512), 0, stream>>>(PO, Pl, WTp, bp, skip,
                                              pre_g, pre_b, WT1, b1, WT2, b2,
                                              post_g, post_b, out);
}